// Round 5
// baseline (2596.738 us; speedup 1.0000x reference)
//
#include <hip/hip_runtime.h>

#define B_ 16
#define T_ 65536
#define H_ 64
#define DEPTH_ 4
#define CHUNK 128
#define NCH (T_ / CHUNK)   // 512 chunks per sequence

typedef _Float16 f16;
typedef f16 f16x8 __attribute__((ext_vector_type(8)));
typedef float f32x4 __attribute__((ext_vector_type(4)));

#define MFMA(a, b, c) __builtin_amdgcn_mfma_f32_16x16x32_f16(a, b, c, 0, 0, 0)
// swizzled word index into hpk: row t (0..127), word k (0..63)
#define SWZ(t, k) ((t) * 64 + ((k) ^ (((t) & 7) << 2)))

// ---------- pack/unpack f16 hi+lo pairs (eff ~2^-21 relative) ----------
__device__ __forceinline__ unsigned pack2(float s) {
    union { f16 h; unsigned short u; } a, b;
    a.h = (f16)s;
    float lo = s - (float)a.h;
    b.h = (f16)lo;
    return (unsigned)a.u | ((unsigned)b.u << 16);
}
__device__ __forceinline__ float unpk(unsigned w) {
    union { unsigned short u; f16 h; } a, b;
    a.u = (unsigned short)(w & 0xffff);
    b.u = (unsigned short)(w >> 16);
    return (float)a.h + (float)b.h;
}
__device__ __forceinline__ f16 hi_of(unsigned w) {
    union { unsigned short u; f16 h; } a; a.u = (unsigned short)(w & 0xffff); return a.h;
}
__device__ __forceinline__ f16 lo_of(unsigned w) {
    union { unsigned short u; f16 h; } a; a.u = (unsigned short)(w >> 16); return a.h;
}

// ---------- hi/lo fragment pairs ----------
struct frag2 { f16x8 hi, lo; };

__device__ __forceinline__ frag2 mk2(const float* p, float scale) {
    frag2 r;
    #pragma unroll
    for (int i = 0; i < 8; ++i) {
        float v = p[i] * scale;
        f16 h = (f16)v;
        r.hi[i] = h;
        r.lo[i] = (f16)(v - (float)h);
    }
    return r;
}
__device__ __forceinline__ frag2 aload2(const float* up, long t, int k) {
    return mk2(up + t * 64 + k, 1.f);
}
__device__ __forceinline__ frag2 aload2(const f16* up, long t, int k) {
    frag2 r;
    r.hi = *(const f16x8*)(up + t * 64 + k);
    #pragma unroll
    for (int i = 0; i < 8; ++i) r.lo[i] = (f16)0.f;
    return r;
}
__device__ __forceinline__ frag2 bfrag2(const float* W, int n, int k0, float scale) {
    return mk2(W + n * 64 + k0, scale);
}
__device__ __forceinline__ f16x8 bfrag1(const float* W, int n, int k0) {
    const float* p = W + n * 64 + k0;
    f16x8 r;
    #pragma unroll
    for (int i = 0; i < 8; ++i) r[i] = (f16)p[i];
    return r;
}
// 3-term high-precision MFMA product: (Ah+Al)x(Bh+Bl) dropping Al*Bl
__device__ __forceinline__ f32x4 mfma3(const frag2& a, const frag2& b, f32x4 acc) {
    acc = MFMA(a.hi, b.hi, acc);
    acc = MFMA(a.lo, b.hi, acc);
    acc = MFMA(a.hi, b.lo, acc);
    return acc;
}

// ---------- carry kernel, layer 0 (u_t = x_t*Win, rank-1) ----------
__global__ __launch_bounds__(64)
void carry_x(const float* __restrict__ x,
             const float* __restrict__ Win,
             const float* __restrict__ nu_log,
             const float* __restrict__ gamma_log,
             const float* __restrict__ Bm,
             float* __restrict__ carry)
{
    const int blk = blockIdx.x;
    const int b = blk >> 9, c = blk & (NCH - 1);
    const int n = threadIdx.x;
    const int t0 = c * CHUNK;

    const float ex = expf(nu_log[n]);
    const float a  = expf(-ex);
    const float g  = expf(gamma_log[n]);
    float bw = 0.f;
    #pragma unroll
    for (int h = 0; h < 64; ++h) bw += Bm[n * 64 + h] * Win[h];
    bw *= g;

    __shared__ float xs[64];
    const float* xp = x + (size_t)b * T_ + t0;
    float s = 0.f;
    for (int bb = 0; bb < CHUNK / 64; ++bb) {
        __syncthreads();
        xs[n] = xp[bb * 64 + n];
        __syncthreads();
        #pragma unroll
        for (int tt = 0; tt < 64; ++tt) s = a * s + bw * xs[tt];
    }
    carry[((size_t)b * NCH + c) * 64 + n] = s;
}

// ---------- carry kernel, layers 1..3 (MFMA Bu + weighted reduce) ----------
template<typename UT>
__global__ __launch_bounds__(256, 2)
void carry_mfma(const UT* __restrict__ hbuf,
                const float* __restrict__ nu_log,
                const float* __restrict__ gamma_log,
                const float* __restrict__ Bm,
                float* __restrict__ carry)
{
    const int blk = blockIdx.x;
    const int b = blk >> 9, c = blk & (NCH - 1);
    const int t0 = c * CHUNK;
    const int tid = threadIdx.x;
    const int w = tid >> 6, lane = tid & 63;
    const int l15 = lane & 15, lq = lane >> 4;

    __shared__ float red[4][64];

    float exn[4];
    frag2 bf[4][2];
    #pragma unroll
    for (int nt = 0; nt < 4; ++nt) {
        int n = nt * 16 + l15;
        exn[nt] = expf(nu_log[n]);
        float g = expf(gamma_log[n]);
        bf[nt][0] = bfrag2(Bm, n, lq * 8,      g);
        bf[nt][1] = bfrag2(Bm, n, 32 + lq * 8, g);
    }

    const UT* up = hbuf + ((size_t)b * T_ + t0) * 64;
    float partial[4] = {0.f, 0.f, 0.f, 0.f};

    #pragma unroll
    for (int tt = 0; tt < 2; ++tt) {
        int tb = 2 * w + tt;
        frag2 a0 = aload2(up, tb * 16 + l15, lq * 8);
        frag2 a1 = aload2(up, tb * 16 + l15, 32 + lq * 8);
        #pragma unroll
        for (int nt = 0; nt < 4; ++nt) {
            f32x4 acc = {0.f, 0.f, 0.f, 0.f};
            acc = mfma3(a0, bf[nt][0], acc);
            acc = mfma3(a1, bf[nt][1], acc);
            #pragma unroll
            for (int r = 0; r < 4; ++r) {
                int t = tb * 16 + lq * 4 + r;
                partial[nt] += expf(-exn[nt] * (float)(CHUNK - 1 - t)) * acc[r];
            }
        }
    }
    #pragma unroll
    for (int nt = 0; nt < 4; ++nt) {
        float v = partial[nt];
        v += __shfl_xor(v, 16);
        v += __shfl_xor(v, 32);
        if (lq == 0) red[w][nt * 16 + l15] = v;
    }
    __syncthreads();
    if (w == 0) {
        float s = red[0][lane] + red[1][lane] + red[2][lane] + red[3][lane];
        carry[((size_t)b * NCH + c) * 64 + lane] = s;
    }
}

// ---------- fused chunk kernel ----------
// LDS: hpk only (35 KB) -> 4 blocks/CU. Wave w owns rows [32w,32w+32) of hpk
// through every phase; only 2 barriers (carry-prefix combine, scan partials).
template<int IN_X, int OUT_FINAL, typename UT>
__global__ __launch_bounds__(256, 4)
void lru_mfma(const float* __restrict__ x,
              UT* hbuf,
              const float* __restrict__ Win,
              const float* __restrict__ nu_log,
              const float* __restrict__ gamma_log,
              const float* __restrict__ Bm,
              const float* __restrict__ Cm,
              const float* __restrict__ Dv,
              const float* __restrict__ Wlin,
              const float* __restrict__ blin,
              const float* __restrict__ Wout,
              const float* __restrict__ carry,
              float* __restrict__ out)
{
    const int blk = blockIdx.x;
    const int b = blk >> 9, c = blk & (NCH - 1);
    const int t0 = c * CHUNK;
    const int tid = threadIdx.x;
    const int w = tid >> 6, lane = tid & 63;
    const int l15 = lane & 15, lq = lane >> 4;

    __shared__ unsigned hpk[CHUNK * 64];   // 32 KB: Bu -> h_prev (packed) -> th (f16, low 32 words/row)
    __shared__ float swv[4][64];
    __shared__ float swv2[4][64];
    __shared__ float hst[64];

    const float ex_n = expf(nu_log[lane]);
    const float a_n  = expf(-ex_n);

    UT* ug = hbuf + ((size_t)b * T_ + t0) * 64;
    const float* xg = x + (size_t)b * T_ + t0;

    // ---- P0a: partial carry-prefix (4-way split over chunks 0..c-1) ----
    {
        const float aL = expf(-ex_n * (float)CHUNK);
        int q = (c + 3) >> 2;
        int lo = w * q; if (lo > c) lo = c;
        int hi = lo + q; if (hi > c) hi = c;
        float p = 0.f;
        const float* cp = carry + (size_t)b * NCH * 64 + lane;
        for (int cc = lo; cc < hi; ++cc) p = aL * p + cp[(size_t)cc * 64];
        swv[w][lane] = p;
    }
    __syncthreads();                       // barrier 1
    if (w == 0) {                          // combine 4 partials -> incoming chunk state
        int q = (c + 3) >> 2;
        float run = 0.f;
        #pragma unroll
        for (int ww = 0; ww < 4; ++ww) {
            int lo = ww * q; if (lo > c) lo = c;
            int hi = lo + q; if (hi > c) hi = c;
            run = run * expf(-ex_n * (float)(CHUNK * (hi - lo))) + swv[ww][lane];
        }
        hst[lane] = run;
    }

    // ---- P1: Bu -> hpk rows of own segment (packed hi/lo) ----
    if (IN_X) {
        float g = expf(gamma_log[lane]);
        float bw = 0.f;
        #pragma unroll
        for (int h = 0; h < 64; ++h) bw += Bm[lane * 64 + h] * Win[h];
        bw *= g;
        #pragma unroll
        for (int i = 0; i < 32; ++i) {
            int t = 32 * w + i;
            hpk[SWZ(t, lane)] = pack2(xg[t] * bw);
        }
    } else {
        #pragma unroll
        for (int tt = 0; tt < 2; ++tt) {
            int tb = 2 * w + tt;
            frag2 a0 = aload2((const UT*)ug, tb * 16 + l15, lq * 8);
            frag2 a1 = aload2((const UT*)ug, tb * 16 + l15, 32 + lq * 8);
            #pragma unroll
            for (int ntg = 0; ntg < 2; ++ntg) {
                #pragma unroll
                for (int q2 = 0; q2 < 2; ++q2) {
                    int nt = ntg * 2 + q2;
                    int n = nt * 16 + l15;
                    float g = expf(gamma_log[n]);
                    frag2 b0 = bfrag2(Bm, n, lq * 8,      g);
                    frag2 b1 = bfrag2(Bm, n, 32 + lq * 8, g);
                    f32x4 a4 = {0.f, 0.f, 0.f, 0.f};
                    a4 = mfma3(a0, b0, a4);
                    a4 = mfma3(a1, b1, a4);
                    #pragma unroll
                    for (int r = 0; r < 4; ++r) {
                        int t = tb * 16 + lq * 4 + r;
                        hpk[SWZ(t, n)] = pack2(a4[r]);
                    }
                }
            }
        }
    }

    // ---- P2a: local scan in place; read Bu at row t, overwrite with local h_{t-1} ----
    {
        float s = 0.f;
        #pragma unroll
        for (int i = 0; i < 32; ++i) {
            int t = 32 * w + i;
            unsigned idx = SWZ(t, lane);
            float bu = unpk(hpk[idx]);
            hpk[idx] = pack2(s);
            s = a_n * s + bu;
        }
        swv2[w][lane] = s;
    }
    __syncthreads();                       // barrier 2

    // ---- P2b: add incoming-state correction inc*a^i to own rows ----
    {
        const float a32 = expf(-ex_n * 32.f);
        float inc = hst[lane];
        for (int ww = 0; ww < w; ++ww) inc = inc * a32 + swv2[ww][lane];
        float qq = inc;
        #pragma unroll
        for (int i = 0; i < 32; ++i) {
            unsigned idx = SWZ(32 * w + i, lane);
            hpk[idx] = pack2(unpk(hpk[idx]) + qq);
            qq *= a_n;
        }
    }

    // ---- P3: y = C.h_prev + Dv*u (diag-MFMA), tanh -> th into low half of own rows ----
    f16* thp = (f16*)hpk;
    #pragma unroll
    for (int tt = 0; tt < 2; ++tt) {
        int tb = 2 * w + tt;
        int trow = tb * 16 + l15;
        int sw = (trow & 7) << 2;
        const unsigned* hw = hpk + trow * 64;
        frag2 afr[2];
        #pragma unroll
        for (int kk = 0; kk < 2; ++kk) {
            int kb = kk * 32 + lq * 8;
            uint4 w0 = *(const uint4*)(hw + ((kb)     ^ sw));
            uint4 w1 = *(const uint4*)(hw + ((kb + 4) ^ sw));
            afr[kk].hi[0]=hi_of(w0.x); afr[kk].hi[1]=hi_of(w0.y); afr[kk].hi[2]=hi_of(w0.z); afr[kk].hi[3]=hi_of(w0.w);
            afr[kk].hi[4]=hi_of(w1.x); afr[kk].hi[5]=hi_of(w1.y); afr[kk].hi[6]=hi_of(w1.z); afr[kk].hi[7]=hi_of(w1.w);
            afr[kk].lo[0]=lo_of(w0.x); afr[kk].lo[1]=lo_of(w0.y); afr[kk].lo[2]=lo_of(w0.z); afr[kk].lo[3]=lo_of(w0.w);
            afr[kk].lo[4]=lo_of(w1.x); afr[kk].lo[5]=lo_of(w1.y); afr[kk].lo[6]=lo_of(w1.z); afr[kk].lo[7]=lo_of(w1.w);
        }
        frag2 au[2];
        if (!IN_X) {
            au[0] = aload2((const UT*)ug, trow, lq * 8);
            au[1] = aload2((const UT*)ug, trow, 32 + lq * 8);
        }
        #pragma unroll
        for (int ntg = 0; ntg < 2; ++ntg) {
            #pragma unroll
            for (int q2 = 0; q2 < 2; ++q2) {
                int nt = ntg * 2 + q2;
                int n = nt * 16 + l15;
                frag2 c0 = bfrag2(Cm, n, lq * 8,      1.f);
                frag2 c1 = bfrag2(Cm, n, 32 + lq * 8, 1.f);
                f32x4 a4 = {0.f, 0.f, 0.f, 0.f};
                a4 = mfma3(afr[0], c0, a4);
                a4 = mfma3(afr[1], c1, a4);
                if (!IN_X) {
                    // Dv diagonal folded in via MFMA: B[k][n] = Dv[n] iff k==n
                    frag2 df;
                    #pragma unroll
                    for (int i2 = 0; i2 < 8; ++i2) { df.hi[i2] = (f16)0.f; df.lo[i2] = (f16)0.f; }
                    int e = ((nt & 1) * 16 + l15) - lq * 8;
                    if (e >= 0 && e < 8) {
                        float dv = Dv[n];
                        f16 h = (f16)dv;
                        df.hi[e] = h; df.lo[e] = (f16)(dv - (float)h);
                    }
                    int kkn = nt >> 1;
                    a4 = MFMA(au[kkn].hi, df.hi, a4);
                    a4 = MFMA(au[kkn].hi, df.lo, a4);
                    a4 = MFMA(au[kkn].lo, df.hi, a4);
                }
                float dwin = IN_X ? Dv[n] * Win[n] : 0.f;
                #pragma unroll
                for (int r = 0; r < 4; ++r) {
                    int t = tb * 16 + lq * 4 + r;
                    float y = a4[r];
                    if (IN_X) y += xg[t] * dwin;
                    float th = y * rsqrtf(1.f + y * y);
                    thp[(t * 64 + ((nt * 8 + (l15 >> 1)) ^ ((t & 7) << 2))) * 2 + (l15 & 1)] = (f16)th;
                }
            }
        }
    }

    // ---- P4: out = Wlin.th + blin + u (identity-diag MFMA) [+ .Wout reduce] ----
    #pragma unroll
    for (int tt = 0; tt < 2; ++tt) {
        int tb = 2 * w + tt;
        int trow = tb * 16 + l15;
        int sw = (trow & 7) << 2;
        f16x8 t0f, t1f;
        {
            union { uint4 u; f16x8 h; } cv0, cv1;
            cv0.u = *(const uint4*)(hpk + trow * 64 + ((lq * 4)      ^ sw));
            cv1.u = *(const uint4*)(hpk + trow * 64 + ((16 + lq * 4) ^ sw));
            t0f = cv0.h; t1f = cv1.h;
        }
        frag2 au[2];
        if (!IN_X) {
            au[0] = aload2((const UT*)ug, trow, lq * 8);
            au[1] = aload2((const UT*)ug, trow, 32 + lq * 8);
        }
        float val[4] = {0.f, 0.f, 0.f, 0.f};
        #pragma unroll
        for (int ntg = 0; ntg < 2; ++ntg) {
            #pragma unroll
            for (int q2 = 0; q2 < 2; ++q2) {
                int nt = ntg * 2 + q2;
                int n = nt * 16 + l15;
                f16x8 w0f = bfrag1(Wlin, n, lq * 8);
                f16x8 w1f = bfrag1(Wlin, n, 32 + lq * 8);
                f32x4 a4 = {0.f, 0.f, 0.f, 0.f};
                a4 = MFMA(t0f, w0f, a4);
                a4 = MFMA(t1f, w1f, a4);
                if (!IN_X) {
                    f16x8 ifr;
                    #pragma unroll
                    for (int i2 = 0; i2 < 8; ++i2) ifr[i2] = (f16)0.f;
                    int e = ((nt & 1) * 16 + l15) - lq * 8;
                    if (e >= 0 && e < 8) ifr[e] = (f16)1.f;
                    int kkn = nt >> 1;
                    a4 = MFMA(au[kkn].hi, ifr, a4);
                    a4 = MFMA(au[kkn].lo, ifr, a4);
                }
                float blj = blin[n];
                float wij = IN_X ? Win[n] : 0.f;
                float woj = OUT_FINAL ? Wout[n] : 0.f;
                #pragma unroll
                for (int r = 0; r < 4; ++r) {
                    int t = tb * 16 + lq * 4 + r;
                    float o = a4[r] + blj;
                    if (IN_X) o += xg[t] * wij;
                    if (OUT_FINAL) {
                        val[r] += o * woj;
                    } else {
                        ug[(size_t)t * 64 + n] = (UT)o;
                    }
                }
            }
        }
        if (OUT_FINAL) {
            #pragma unroll
            for (int r = 0; r < 4; ++r) {
                float p = val[r];
                p += __shfl_xor(p, 1);
                p += __shfl_xor(p, 2);
                p += __shfl_xor(p, 4);
                p += __shfl_xor(p, 8);
                if (l15 == 0) out[(size_t)b * T_ + t0 + tb * 16 + lq * 4 + r] = p;
            }
        }
    }
}

// ---------- host ----------
template<typename UT>
static void run_all(const float* x, const float* Win,
                    const float* nu, const float* ga,
                    const float* Bm, const float* Cm,
                    const float* Dv, const float* Wl,
                    const float* bl, const float* Wo,
                    UT* hbuf, float* carry, float* out, hipStream_t stream)
{
    dim3 grid(B_ * NCH), blk256(256), blk64(64);
    for (int i = 0; i < DEPTH_; ++i) {
        const float *nui = nu + i * 64, *gai = ga + i * 64;
        const float *Bmi = Bm + i * 64 * 64, *Cmi = Cm + i * 64 * 64;
        const float *Dvi = Dv + i * 64, *Wli = Wl + i * 64 * 64, *bli = bl + i * 64;
        if (i == 0)
            carry_x<<<grid, blk64, 0, stream>>>(x, Win, nui, gai, Bmi, carry);
        else
            carry_mfma<UT><<<grid, blk256, 0, stream>>>(hbuf, nui, gai, Bmi, carry);
        if (i == 0)
            lru_mfma<1, 0, UT><<<grid, blk256, 0, stream>>>(x, hbuf, Win, nui, gai, Bmi, Cmi, Dvi, Wli, bli, Wo, carry, out);
        else if (i == DEPTH_ - 1)
            lru_mfma<0, 1, UT><<<grid, blk256, 0, stream>>>(x, hbuf, Win, nui, gai, Bmi, Cmi, Dvi, Wli, bli, Wo, carry, out);
        else
            lru_mfma<0, 0, UT><<<grid, blk256, 0, stream>>>(x, hbuf, Win, nui, gai, Bmi, Cmi, Dvi, Wli, bli, Wo, carry, out);
    }
}

extern "C" void kernel_launch(void* const* d_in, const int* in_sizes, int n_in,
                              void* d_out, int out_size, void* d_ws, size_t ws_size,
                              hipStream_t stream)
{
    const float* x   = (const float*)d_in[0];
    const float* Win = (const float*)d_in[1];
    const float* nu  = (const float*)d_in[2];
    const float* ga  = (const float*)d_in[3];
    const float* Bm  = (const float*)d_in[4];
    const float* Cm  = (const float*)d_in[5];
    const float* Dv  = (const float*)d_in[6];
    const float* Wl  = (const float*)d_in[7];
    const float* bl  = (const float*)d_in[8];
    const float* Wo  = (const float*)d_in[9];
    float* out = (float*)d_out;

    const size_t act = (size_t)B_ * T_ * H_;
    const size_t carry_bytes = (size_t)B_ * NCH * 64 * sizeof(float);

    if (ws_size >= act * sizeof(float) + carry_bytes) {
        float* hbuf  = (float*)d_ws;
        float* carry = (float*)((char*)d_ws + act * sizeof(float));
        run_all<float>(x, Win, nu, ga, Bm, Cm, Dv, Wl, bl, Wo, hbuf, carry, out, stream);
    } else {
        f16* hbuf = (f16*)d_ws;
        float* carry = (float*)((char*)d_ws + act * sizeof(f16));
        run_all<f16>(x, Win, nu, ga, Bm, Cm, Dv, Wl, bl, Wo, hbuf, carry, out, stream);
    }
}

// Round 6
// 2316.639 us; speedup vs baseline: 1.1209x; 1.1209x over previous
//
#include <hip/hip_runtime.h>

#define B_ 16
#define T_ 65536
#define H_ 64
#define DEPTH_ 4
#define CHUNK 128
#define NCH (T_ / CHUNK)   // 512 chunks per sequence

typedef _Float16 f16;
typedef f16 f16x8 __attribute__((ext_vector_type(8)));
typedef float f32x4 __attribute__((ext_vector_type(4)));

#define MFMA(a, b, c) __builtin_amdgcn_mfma_f32_16x16x32_f16(a, b, c, 0, 0, 0)
// swizzled word index into hpk: row t (0..127), word k (0..63)
#define SWZ(t, k) ((t) * 64 + ((k) ^ (((t) & 7) << 2)))

// staged-output word index (upper 32 words of each row), col j (0..63)
__device__ __forceinline__ int stg_word(int t, int j) {
    int g = j >> 1;
    return t * 64 + 32 + ((((g & ~3) ^ ((t & 7) << 2))) | (g & 3));
}

// ---------- pack/unpack f16 hi+lo pairs (eff ~2^-21 relative) ----------
__device__ __forceinline__ unsigned pack2(float s) {
    union { f16 h; unsigned short u; } a, b;
    a.h = (f16)s;
    float lo = s - (float)a.h;
    b.h = (f16)lo;
    return (unsigned)a.u | ((unsigned)b.u << 16);
}
__device__ __forceinline__ float unpk(unsigned w) {
    union { unsigned short u; f16 h; } a, b;
    a.u = (unsigned short)(w & 0xffff);
    b.u = (unsigned short)(w >> 16);
    return (float)a.h + (float)b.h;
}
__device__ __forceinline__ f16 hi_of(unsigned w) {
    union { unsigned short u; f16 h; } a; a.u = (unsigned short)(w & 0xffff); return a.h;
}
__device__ __forceinline__ f16 lo_of(unsigned w) {
    union { unsigned short u; f16 h; } a; a.u = (unsigned short)(w >> 16); return a.h;
}

// ---------- fragments ----------
struct frag2 { f16x8 hi, lo; };

__device__ __forceinline__ frag2 mk2(const float* p, float scale) {
    frag2 r;
    #pragma unroll
    for (int i = 0; i < 8; ++i) {
        float v = p[i] * scale;
        f16 h = (f16)v;
        r.hi[i] = h;
        r.lo[i] = (f16)(v - (float)h);
    }
    return r;
}
__device__ __forceinline__ frag2 bfrag2(const float* W, int n, int k0, float scale) {
    return mk2(W + n * 64 + k0, scale);
}
__device__ __forceinline__ f16x8 bfrag1(const float* W, int n, int k0) {
    const float* p = W + n * 64 + k0;
    f16x8 r;
    #pragma unroll
    for (int i = 0; i < 8; ++i) r[i] = (f16)p[i];
    return r;
}
__device__ __forceinline__ f16x8 aload1(const f16* up, long t, int k) {
    return *(const f16x8*)(up + t * 64 + k);
}
// 3-term high-precision MFMA product: (Ah+Al)x(Bh+Bl) dropping Al*Bl
__device__ __forceinline__ f32x4 mfma3(const frag2& a, const frag2& b, f32x4 acc) {
    acc = MFMA(a.hi, b.hi, acc);
    acc = MFMA(a.lo, b.hi, acc);
    acc = MFMA(a.hi, b.lo, acc);
    return acc;
}

// ---------- carry kernel, layer 0 (u_t = x_t*Win, rank-1) ----------
__global__ __launch_bounds__(64)
void carry_x(const float* __restrict__ x,
             const float* __restrict__ Win,
             const float* __restrict__ nu_log,
             const float* __restrict__ gamma_log,
             const float* __restrict__ Bm,
             float* __restrict__ carry)
{
    const int blk = blockIdx.x;
    const int b = blk >> 9, c = blk & (NCH - 1);
    const int n = threadIdx.x;
    const int t0 = c * CHUNK;

    const float ex = expf(nu_log[n]);
    const float a  = expf(-ex);
    const float g  = expf(gamma_log[n]);
    float bw = 0.f;
    #pragma unroll
    for (int h = 0; h < 64; ++h) bw += Bm[n * 64 + h] * Win[h];
    bw *= g;

    __shared__ float xs[64];
    const float* xp = x + (size_t)b * T_ + t0;
    float s = 0.f;
    for (int bb = 0; bb < CHUNK / 64; ++bb) {
        __syncthreads();
        xs[n] = xp[bb * 64 + n];
        __syncthreads();
        #pragma unroll
        for (int tt = 0; tt < 64; ++tt) s = a * s + bw * xs[tt];
    }
    carry[((size_t)b * NCH + c) * 64 + n] = s;
}

// ---------- in-place exclusive decay-scan of per-chunk carries ----------
// after: carry[b,c,n] = h-state at start of chunk c
__global__ __launch_bounds__(256)
void scan_carry(const float* __restrict__ nu_log, float* __restrict__ carry)
{
    const int b = blockIdx.x;
    const int tid = threadIdx.x;
    const int n = tid & 63, q = tid >> 6;
    const float ex = expf(nu_log[n]);
    const float aL = expf(-ex * (float)CHUNK);
    float* cp = carry + (size_t)b * NCH * 64 + n;
    __shared__ float part[4][64];

    const int SEG = NCH / 4;
    const int base = q * SEG;
    float p = 0.f;
    #pragma unroll 4
    for (int i = 0; i < SEG; ++i) {
        float v = cp[(size_t)(base + i) * 64];
        cp[(size_t)(base + i) * 64] = p;
        p = aL * p + v;
    }
    part[q][n] = p;
    __syncthreads();
    if (q > 0) {
        const float aLS = expf(-ex * (float)(CHUNK * SEG));
        float inc = 0.f;
        for (int qq = 0; qq < q; ++qq) inc = inc * aLS + part[qq][n];
        float qv = inc;
        #pragma unroll 4
        for (int i = 0; i < SEG; ++i) {
            cp[(size_t)(base + i) * 64] += qv;
            qv *= aL;
        }
    }
}

// ---------- fused chunk kernel ----------
// hpk rows wave-owned through all phases. 2 barriers.
// P1 Bu GEMM -> hpk; P2 scan; P3 C GEMM + tanh -> th (low words);
// P4 Wlin GEMM + residual -> staged (high words) -> coalesced store + next-layer carry GEMM.
template<int IN_X, int OUT_FINAL>
__global__ __launch_bounds__(256, 4)
void lru_fused(const float* __restrict__ x,
               f16* __restrict__ ubuf,
               const float* __restrict__ Win,
               const float* __restrict__ nu_log,
               const float* __restrict__ gamma_log,
               const float* __restrict__ Bm,
               const float* __restrict__ Cm,
               const float* __restrict__ Dv,
               const float* __restrict__ Wlin,
               const float* __restrict__ blin,
               const float* __restrict__ Wout,
               const float* __restrict__ nu_next,
               const float* __restrict__ ga_next,
               const float* __restrict__ Bm_next,
               float* __restrict__ carry,      // in: prefix for this layer; out: raw carry for next
               float* __restrict__ out)
{
    const int blk = blockIdx.x;
    const int b = blk >> 9, c = blk & (NCH - 1);
    const int t0 = c * CHUNK;
    const int tid = threadIdx.x;
    const int w = tid >> 6, lane = tid & 63;
    const int l15 = lane & 15, lq = lane >> 4;

    __shared__ unsigned hpk[CHUNK * 64];   // 32 KB
    __shared__ float swv2[4][64];
    __shared__ float red[4][64];

    const float ex_n = expf(nu_log[lane]);
    const float a_n  = expf(-ex_n);

    f16* ug = ubuf + ((size_t)b * T_ + t0) * 64;
    const float* xg = x + (size_t)b * T_ + t0;

    const float hst = carry[((size_t)b * NCH + c) * 64 + lane];   // precomputed prefix

    // u A-frags (hi only; u is f16 in memory), register-resident for P1/P3/P4
    f16x8 ahu[2][2];
    if (!IN_X) {
        #pragma unroll
        for (int tt = 0; tt < 2; ++tt) {
            int trow = (2 * w + tt) * 16 + l15;
            ahu[tt][0] = aload1(ug, trow, lq * 8);
            ahu[tt][1] = aload1(ug, trow, 32 + lq * 8);
        }
    }

    // ---- P1: Bu -> hpk (packed hi/lo) ----
    if (IN_X) {
        float g = expf(gamma_log[lane]);
        float bw = 0.f;
        #pragma unroll
        for (int h = 0; h < 64; ++h) bw += Bm[lane * 64 + h] * Win[h];
        bw *= g;
        #pragma unroll
        for (int i = 0; i < 32; ++i) {
            int t = 32 * w + i;
            hpk[SWZ(t, lane)] = pack2(xg[t] * bw);
        }
    } else {
        #pragma unroll
        for (int tt = 0; tt < 2; ++tt) {
            int tb = 2 * w + tt;
            #pragma unroll
            for (int nt = 0; nt < 4; ++nt) {
                int n = nt * 16 + l15;
                float g = expf(gamma_log[n]);
                frag2 b0 = bfrag2(Bm, n, lq * 8,      g);
                frag2 b1 = bfrag2(Bm, n, 32 + lq * 8, g);
                f32x4 a4 = {0.f, 0.f, 0.f, 0.f};
                a4 = MFMA(ahu[tt][0], b0.hi, a4);
                a4 = MFMA(ahu[tt][0], b0.lo, a4);
                a4 = MFMA(ahu[tt][1], b1.hi, a4);
                a4 = MFMA(ahu[tt][1], b1.lo, a4);
                #pragma unroll
                for (int r = 0; r < 4; ++r)
                    hpk[SWZ(tb * 16 + lq * 4 + r, n)] = pack2(a4[r]);
            }
        }
    }

    // ---- P2a: local scan in place; row t -> local h_{t-1} ----
    {
        float s = 0.f;
        #pragma unroll
        for (int i = 0; i < 32; ++i) {
            int t = 32 * w + i;
            unsigned idx = SWZ(t, lane);
            float bu = unpk(hpk[idx]);
            hpk[idx] = pack2(s);
            s = a_n * s + bu;
        }
        swv2[w][lane] = s;
    }
    __syncthreads();                       // barrier 1

    // ---- P2b: add incoming-state correction inc*a^i to own rows ----
    {
        const float a32 = expf(-ex_n * 32.f);
        float inc = hst;
        for (int ww = 0; ww < w; ++ww) inc = inc * a32 + swv2[ww][lane];
        float qq = inc;
        #pragma unroll
        for (int i = 0; i < 32; ++i) {
            unsigned idx = SWZ(32 * w + i, lane);
            hpk[idx] = pack2(unpk(hpk[idx]) + qq);
            qq *= a_n;
        }
    }

    // ---- P3: y = C.h_prev + Dv*u, tanh -> th into low 32 words of own rows ----
    f16* thp = (f16*)hpk;
    #pragma unroll
    for (int tt = 0; tt < 2; ++tt) {
        int tb = 2 * w + tt;
        int trow = tb * 16 + l15;
        int sw = (trow & 7) << 2;
        const unsigned* hw = hpk + trow * 64;
        frag2 afr[2];
        #pragma unroll
        for (int kk = 0; kk < 2; ++kk) {
            int kb = kk * 32 + lq * 8;
            uint4 w0 = *(const uint4*)(hw + ((kb)     ^ sw));
            uint4 w1 = *(const uint4*)(hw + ((kb + 4) ^ sw));
            afr[kk].hi[0]=hi_of(w0.x); afr[kk].hi[1]=hi_of(w0.y); afr[kk].hi[2]=hi_of(w0.z); afr[kk].hi[3]=hi_of(w0.w);
            afr[kk].hi[4]=hi_of(w1.x); afr[kk].hi[5]=hi_of(w1.y); afr[kk].hi[6]=hi_of(w1.z); afr[kk].hi[7]=hi_of(w1.w);
            afr[kk].lo[0]=lo_of(w0.x); afr[kk].lo[1]=lo_of(w0.y); afr[kk].lo[2]=lo_of(w0.z); afr[kk].lo[3]=lo_of(w0.w);
            afr[kk].lo[4]=lo_of(w1.x); afr[kk].lo[5]=lo_of(w1.y); afr[kk].lo[6]=lo_of(w1.z); afr[kk].lo[7]=lo_of(w1.w);
        }
        #pragma unroll
        for (int nt = 0; nt < 4; ++nt) {
            int n = nt * 16 + l15;
            frag2 c0 = bfrag2(Cm, n, lq * 8,      1.f);
            frag2 c1 = bfrag2(Cm, n, 32 + lq * 8, 1.f);
            f32x4 a4 = {0.f, 0.f, 0.f, 0.f};
            a4 = mfma3(afr[0], c0, a4);
            a4 = mfma3(afr[1], c1, a4);
            if (!IN_X) {
                frag2 df;
                #pragma unroll
                for (int i2 = 0; i2 < 8; ++i2) { df.hi[i2] = (f16)0.f; df.lo[i2] = (f16)0.f; }
                int e = ((nt & 1) * 16 + l15) - lq * 8;
                if (e >= 0 && e < 8) {
                    float dv = Dv[n];
                    f16 h = (f16)dv;
                    df.hi[e] = h; df.lo[e] = (f16)(dv - (float)h);
                }
                int kkn = nt >> 1;
                a4 = MFMA(ahu[tt][kkn], df.hi, a4);
                a4 = MFMA(ahu[tt][kkn], df.lo, a4);
            }
            float dwin = IN_X ? Dv[n] * Win[n] : 0.f;
            #pragma unroll
            for (int r = 0; r < 4; ++r) {
                int t = tb * 16 + lq * 4 + r;
                float y = a4[r];
                if (IN_X) y += xg[t] * dwin;
                float th = y * rsqrtf(1.f + y * y);
                thp[(t * 64 + ((nt * 8 + (l15 >> 1)) ^ ((t & 7) << 2))) * 2 + (l15 & 1)] = (f16)th;
            }
        }
    }

    // ---- P4: o = Wlin.th + blin + u; stage to high words / final reduce ----
    f16* stg = (f16*)hpk;
    #pragma unroll
    for (int tt = 0; tt < 2; ++tt) {
        int tb = 2 * w + tt;
        int trow = tb * 16 + l15;
        int sw = (trow & 7) << 2;
        f16x8 t0f, t1f;
        {
            union { uint4 u; f16x8 h; } cv0, cv1;
            cv0.u = *(const uint4*)(hpk + trow * 64 + ((lq * 4)      ^ sw));
            cv1.u = *(const uint4*)(hpk + trow * 64 + ((16 + lq * 4) ^ sw));
            t0f = cv0.h; t1f = cv1.h;
        }
        float val[4] = {0.f, 0.f, 0.f, 0.f};
        #pragma unroll
        for (int nt = 0; nt < 4; ++nt) {
            int n = nt * 16 + l15;
            f16x8 w0f = bfrag1(Wlin, n, lq * 8);
            f16x8 w1f = bfrag1(Wlin, n, 32 + lq * 8);
            f32x4 a4 = {0.f, 0.f, 0.f, 0.f};
            a4 = MFMA(t0f, w0f, a4);
            a4 = MFMA(t1f, w1f, a4);
            if (!IN_X) {
                f16x8 ifr;
                #pragma unroll
                for (int i2 = 0; i2 < 8; ++i2) ifr[i2] = (f16)0.f;
                int e = ((nt & 1) * 16 + l15) - lq * 8;
                if (e >= 0 && e < 8) ifr[e] = (f16)1.f;
                a4 = MFMA(ahu[tt][nt >> 1], ifr, a4);
            }
            float blj = blin[n];
            float wij = IN_X ? Win[n] : 0.f;
            float woj = OUT_FINAL ? Wout[n] : 0.f;
            #pragma unroll
            for (int r = 0; r < 4; ++r) {
                int t = tb * 16 + lq * 4 + r;
                float o = a4[r] + blj;
                if (IN_X) o += xg[t] * wij;
                if (OUT_FINAL) {
                    val[r] += o * woj;
                } else {
                    stg[stg_word(t, n) * 2 + (n & 1)] = (f16)o;
                }
            }
        }
        if (OUT_FINAL) {
            #pragma unroll
            for (int r = 0; r < 4; ++r) {
                float p = val[r];
                p += __shfl_xor(p, 1);
                p += __shfl_xor(p, 2);
                p += __shfl_xor(p, 4);
                p += __shfl_xor(p, 8);
                if (l15 == 0) out[(size_t)b * T_ + t0 + tb * 16 + lq * 4 + r] = p;
            }
        }
    }

    if (!OUT_FINAL) {
        // ---- coalesced store of own 32 rows from staged LDS ----
        #pragma unroll
        for (int i = 0; i < 4; ++i) {
            int row = 32 * w + i * 8 + (lane >> 3);
            int g = 4 * (lane & 7);
            int word = row * 64 + 32 + (g ^ ((row & 7) << 2));
            union { uint4 u; f16x8 h; } cv;
            cv.u = *(const uint4*)(hpk + word);
            *(f16x8*)(ug + (size_t)row * 64 + 8 * (lane & 7)) = cv.h;
        }

        // ---- next-layer carry GEMM from staged tile ----
        float exnx[4];
        #pragma unroll
        for (int nt = 0; nt < 4; ++nt) exnx[nt] = expf(nu_next[nt * 16 + l15]);
        float partial[4] = {0.f, 0.f, 0.f, 0.f};
        #pragma unroll
        for (int tt = 0; tt < 2; ++tt) {
            int tb = 2 * w + tt;
            int arow = tb * 16 + l15;
            int mask = (arow & 7) << 2;
            union { uint4 u; f16x8 h; } av0, av1;
            av0.u = *(const uint4*)(hpk + arow * 64 + 32 + ((4 * lq) ^ mask));
            av1.u = *(const uint4*)(hpk + arow * 64 + 32 + ((16 + 4 * lq) ^ mask));
            #pragma unroll
            for (int nt = 0; nt < 4; ++nt) {
                int n = nt * 16 + l15;
                float gnx = expf(ga_next[n]);
                frag2 b0 = bfrag2(Bm_next, n, lq * 8,      gnx);
                frag2 b1 = bfrag2(Bm_next, n, 32 + lq * 8, gnx);
                f32x4 a4 = {0.f, 0.f, 0.f, 0.f};
                a4 = MFMA(av0.h, b0.hi, a4);
                a4 = MFMA(av0.h, b0.lo, a4);
                a4 = MFMA(av1.h, b1.hi, a4);
                a4 = MFMA(av1.h, b1.lo, a4);
                #pragma unroll
                for (int r = 0; r < 4; ++r) {
                    int t = tb * 16 + lq * 4 + r;
                    partial[nt] += expf(-exnx[nt] * (float)(CHUNK - 1 - t)) * a4[r];
                }
            }
        }
        #pragma unroll
        for (int nt = 0; nt < 4; ++nt) {
            float v = partial[nt];
            v += __shfl_xor(v, 16);
            v += __shfl_xor(v, 32);
            if (lq == 0) red[w][nt * 16 + l15] = v;
        }
        __syncthreads();                   // barrier 2
        if (w == 0)
            carry[((size_t)b * NCH + c) * 64 + lane] =
                red[0][lane] + red[1][lane] + red[2][lane] + red[3][lane];
    }
}

// ---------- host ----------
extern "C" void kernel_launch(void* const* d_in, const int* in_sizes, int n_in,
                              void* d_out, int out_size, void* d_ws, size_t ws_size,
                              hipStream_t stream)
{
    const float* x   = (const float*)d_in[0];
    const float* Win = (const float*)d_in[1];
    const float* nu  = (const float*)d_in[2];
    const float* ga  = (const float*)d_in[3];
    const float* Bm  = (const float*)d_in[4];
    const float* Cm  = (const float*)d_in[5];
    const float* Dv  = (const float*)d_in[6];
    const float* Wl  = (const float*)d_in[7];
    const float* bl  = (const float*)d_in[8];
    const float* Wo  = (const float*)d_in[9];
    float* out = (float*)d_out;

    const size_t act = (size_t)B_ * T_ * H_;
    f16* ubuf = (f16*)d_ws;
    float* carry = (float*)((char*)d_ws + act * sizeof(f16));

    dim3 grid(B_ * NCH), blk256(256), blk64(64), gscan(B_);

    const float *nuL[DEPTH_], *gaL[DEPTH_], *BmL[DEPTH_], *CmL[DEPTH_],
                *DvL[DEPTH_], *WlL[DEPTH_], *blL[DEPTH_];
    for (int i = 0; i < DEPTH_; ++i) {
        nuL[i] = nu + i * 64; gaL[i] = ga + i * 64;
        BmL[i] = Bm + i * 64 * 64; CmL[i] = Cm + i * 64 * 64;
        DvL[i] = Dv + i * 64; WlL[i] = Wl + i * 64 * 64; blL[i] = bl + i * 64;
    }

    carry_x<<<grid, blk64, 0, stream>>>(x, Win, nuL[0], gaL[0], BmL[0], carry);
    scan_carry<<<gscan, blk256, 0, stream>>>(nuL[0], carry);
    lru_fused<1, 0><<<grid, blk256, 0, stream>>>(x, ubuf, Win, nuL[0], gaL[0], BmL[0], CmL[0],
                                                 DvL[0], WlL[0], blL[0], Wo,
                                                 nuL[1], gaL[1], BmL[1], carry, out);
    scan_carry<<<gscan, blk256, 0, stream>>>(nuL[1], carry);
    lru_fused<0, 0><<<grid, blk256, 0, stream>>>(x, ubuf, Win, nuL[1], gaL[1], BmL[1], CmL[1],
                                                 DvL[1], WlL[1], blL[1], Wo,
                                                 nuL[2], gaL[2], BmL[2], carry, out);
    scan_carry<<<gscan, blk256, 0, stream>>>(nuL[2], carry);
    lru_fused<0, 0><<<grid, blk256, 0, stream>>>(x, ubuf, Win, nuL[2], gaL[2], BmL[2], CmL[2],
                                                 DvL[2], WlL[2], blL[2], Wo,
                                                 nuL[3], gaL[3], BmL[3], carry, out);
    scan_carry<<<gscan, blk256, 0, stream>>>(nuL[3], carry);
    lru_fused<0, 1><<<grid, blk256, 0, stream>>>(x, ubuf, Win, nuL[3], gaL[3], BmL[3], CmL[3],
                                                 DvL[3], WlL[3], blL[3], Wo,
                                                 nuL[3], gaL[3], BmL[3], carry, out);
}

// Round 8
// 1409.877 us; speedup vs baseline: 1.8418x; 1.6432x over previous
//
#include <hip/hip_runtime.h>

#define B_ 16
#define T_ 65536
#define H_ 64
#define DEPTH_ 4
#define CHUNK 128
#define NCH (T_ / CHUNK)   // 512 chunks per sequence

typedef _Float16 f16;
typedef f16 f16x8 __attribute__((ext_vector_type(8)));
typedef float f32x4 __attribute__((ext_vector_type(4)));
typedef unsigned u32x4 __attribute__((ext_vector_type(4)));

#define MFMA(a, b, c) __builtin_amdgcn_mfma_f32_16x16x32_f16(a, b, c, 0, 0, 0)
// swizzled word index into hpk: row t (0..127), word k (0..63)
#define SWZ(t, k) ((t) * 64 + ((k) ^ (((t) & 7) << 2)))

union U4F8 { u32x4 u; f16x8 h; };

__device__ __forceinline__ f16x8 ldfrag(const f16* p) { return *(const f16x8*)p; }

// ---------- prep: pack weights to f16 hi/lo, decay tables, scalars ----------
// sc per layer (stride 320 floats): [0]=a, [64]=Dv, [128]=bw(=g*Bm.Win), [192]=Dv*Win, [256]=Win
__global__ __launch_bounds__(256)
void prep(const float* __restrict__ Win, const float* __restrict__ nu,
          const float* __restrict__ ga, const float* __restrict__ Bm,
          const float* __restrict__ Cm, const float* __restrict__ Dv,
          const float* __restrict__ Wl,
          f16* __restrict__ BmH, f16* __restrict__ BmL,
          f16* __restrict__ CmH, f16* __restrict__ CmL,
          f16* __restrict__ WlH, float* __restrict__ atab, float* __restrict__ sc)
{
    const int tid = threadIdx.x;
    for (int l = 0; l < DEPTH_; ++l) {
        for (int idx = tid; idx < 4096; idx += 256) {
            int n = idx >> 6;
            float g = expf(ga[l * 64 + n]);
            float v = Bm[l * 4096 + idx] * g;
            f16 h = (f16)v;
            BmH[l * 4096 + idx] = h;
            BmL[l * 4096 + idx] = (f16)(v - (float)h);
            float cv = Cm[l * 4096 + idx];
            h = (f16)cv;
            CmH[l * 4096 + idx] = h;
            CmL[l * 4096 + idx] = (f16)(cv - (float)h);
            WlH[l * 4096 + idx] = (f16)Wl[l * 4096 + idx];
        }
        if (tid < 64) {
            int n = tid;
            float ex = expf(nu[l * 64 + n]);
            float a = expf(-ex);
            float g = expf(ga[l * 64 + n]);
            sc[l * 320 + n] = a;
            sc[l * 320 + 64 + n] = Dv[l * 64 + n];
            float bw = 0.f;
            for (int h2 = 0; h2 < 64; ++h2) bw += Bm[l * 4096 + n * 64 + h2] * Win[h2];
            sc[l * 320 + 128 + n] = bw * g;
            sc[l * 320 + 192 + n] = Dv[l * 64 + n] * Win[n];
            sc[l * 320 + 256 + n] = Win[n];
        }
        for (int idx = tid; idx < 8192; idx += 256) {
            int n = idx >> 7, j = idx & 127;
            float ex = expf(nu[l * 64 + n]);
            atab[l * 8192 + idx] = expf(-ex * (float)j);
        }
    }
}

// ---------- raw carry for layer 0 (u_t = x_t*Win, rank-1) ----------
__global__ __launch_bounds__(64)
void carry_x(const float* __restrict__ x, const float* __restrict__ sc0,
             float* __restrict__ carry)
{
    const int blk = blockIdx.x;
    const int b = blk >> 9, c = blk & (NCH - 1);
    const int n = threadIdx.x;
    const float a  = sc0[n];
    const float bw = sc0[128 + n];
    __shared__ float xs[64];
    const float* xp = x + (size_t)b * T_ + c * CHUNK;
    float s = 0.f;
    for (int bb = 0; bb < CHUNK / 64; ++bb) {
        __syncthreads();
        xs[n] = xp[bb * 64 + n];
        __syncthreads();
        #pragma unroll
        for (int tt = 0; tt < 64; ++tt) s = a * s + bw * xs[tt];
    }
    carry[((size_t)b * NCH + c) * 64 + n] = s;
}

// ---------- in-place exclusive decay-scan of per-chunk carries ----------
__global__ __launch_bounds__(256)
void scan_carry(const float* __restrict__ nu_log, float* __restrict__ carry)
{
    const int b = blockIdx.x;
    const int tid = threadIdx.x;
    const int n = tid & 63, q = tid >> 6;
    const float ex = expf(nu_log[n]);
    const float aL = expf(-ex * (float)CHUNK);
    float* cp = carry + (size_t)b * NCH * 64 + n;
    __shared__ float part[4][64];

    const int SEG = NCH / 4;
    const int base = q * SEG;
    float p = 0.f;
    #pragma unroll 4
    for (int i = 0; i < SEG; ++i) {
        float v = cp[(size_t)(base + i) * 64];
        cp[(size_t)(base + i) * 64] = p;
        p = aL * p + v;
    }
    part[q][n] = p;
    __syncthreads();
    if (q > 0) {
        const float aLS = expf(-ex * (float)(CHUNK * SEG));
        float inc = 0.f;
        for (int qq = 0; qq < q; ++qq) inc = inc * aLS + part[qq][n];
        float qv = inc;
        #pragma unroll 4
        for (int i = 0; i < SEG; ++i) {
            cp[(size_t)(base + i) * 64] += qv;
            qv *= aL;
        }
    }
}

struct LPrep {
    const f16 *BmH, *BmL, *CmH, *CmL, *WlH;  // this layer (gamma folded into Bm)
    const float *av, *dvv, *bw, *dwin, *win; // this-layer scalars
    const f16 *BmHn, *BmLn;                  // next-layer Bm (gamma folded)
    const float *atabn;                      // next-layer decay table a^j
    const float *blin, *Wout;
};

// ---------- fused chunk kernel ----------
template<int IN_X, int OUT_FINAL>
__global__ __launch_bounds__(256, 4)
void lru_fused(const float* __restrict__ x, f16* __restrict__ ubuf,
               LPrep P, float* __restrict__ carry, float* __restrict__ out)
{
    const int blk = blockIdx.x;
    const int b = blk >> 9, c = blk & (NCH - 1);
    const int t0 = c * CHUNK;
    const int tid = threadIdx.x;
    const int w = tid >> 6, lane = tid & 63;
    const int l15 = lane & 15, lq = lane >> 4;

    __shared__ float hpk[CHUNK * 64];   // 32 KB fp32: holds h_prev -> th -> staged o
    __shared__ float swv[4][64];
    __shared__ float red[4][64];

    f16* ug = ubuf + ((size_t)b * T_ + t0) * 64;
    const float* xg = x + (size_t)b * T_ + t0;

    // u A-frags (nontemporal, read-once)
    f16x8 ahu[2][2];
    if (!IN_X) {
        #pragma unroll
        for (int tt = 0; tt < 2; ++tt) {
            const f16* p = ug + (size_t)((2 * w + tt) * 16 + l15) * 64;
            U4F8 r0, r1;
            r0.u = __builtin_nontemporal_load((const u32x4*)(p + lq * 8));
            r1.u = __builtin_nontemporal_load((const u32x4*)(p + 32 + lq * 8));
            ahu[tt][0] = r0.h;
            ahu[tt][1] = r1.h;
        }
    }

    float av4[4];
    #pragma unroll
    for (int nt = 0; nt < 4; ++nt) av4[nt] = P.av[nt * 16 + l15];

    float xv[2][4];
    if (IN_X) {
        #pragma unroll
        for (int tt = 0; tt < 2; ++tt)
            #pragma unroll
            for (int r = 0; r < 4; ++r)
                xv[tt][r] = xg[32 * w + 16 * tt + 4 * lq + r];
    }

    // ---- P1: Bu in registers (MFMA C-layout: row t=tb*16+lq*4+r, col n=nt*16+l15) ----
    f32x4 acc[4][2];
    if (IN_X) {
        #pragma unroll
        for (int nt = 0; nt < 4; ++nt) {
            float bwn = P.bw[nt * 16 + l15];
            #pragma unroll
            for (int tt = 0; tt < 2; ++tt)
                #pragma unroll
                for (int r = 0; r < 4; ++r) acc[nt][tt][r] = xv[tt][r] * bwn;
        }
    } else {
        #pragma unroll
        for (int nt = 0; nt < 4; ++nt) {
            int n = nt * 16 + l15;
            f16x8 bh0 = ldfrag(P.BmH + n * 64 + lq * 8);
            f16x8 bh1 = ldfrag(P.BmH + n * 64 + 32 + lq * 8);
            f16x8 bl0 = ldfrag(P.BmL + n * 64 + lq * 8);
            f16x8 bl1 = ldfrag(P.BmL + n * 64 + 32 + lq * 8);
            #pragma unroll
            for (int tt = 0; tt < 2; ++tt) {
                f32x4 a4v = {0.f, 0.f, 0.f, 0.f};
                a4v = MFMA(ahu[tt][0], bh0, a4v);
                a4v = MFMA(ahu[tt][0], bl0, a4v);
                a4v = MFMA(ahu[tt][1], bh1, a4v);
                a4v = MFMA(ahu[tt][1], bl1, a4v);
                acc[nt][tt] = a4v;
            }
        }
    }

    // ---- P2: register scan with decayed shfl (per n, over t) ----
    float Wb[4][2];
    #pragma unroll
    for (int nt = 0; nt < 4; ++nt) {
        float a = av4[nt], a2 = a * a, a4 = a2 * a2, a8 = a4 * a4, a16 = a8 * a8;
        float P0incl = 0.f;
        #pragma unroll
        for (int tt = 0; tt < 2; ++tt) {
            f32x4 xs = acc[nt][tt];
            float L0 = xs[0];
            float L1 = a * L0 + xs[1];
            float L2 = a * L1 + xs[2];
            float Cv = a * L2 + xs[3];
            float u1 = __shfl_up(Cv, 16);
            float t1 = Cv + ((lq >= 1) ? a4 * u1 : 0.f);
            float u2 = __shfl_up(t1, 32);
            float Pv = t1 + ((lq >= 2) ? a8 * u2 : 0.f);
            float E = __shfl_up(Pv, 16);
            E = (lq == 0) ? 0.f : E;
            if (tt == 0) { Wb[nt][0] = E; P0incl = Pv; }
            else {
                float B0 = __shfl(P0incl, 48 + l15);
                float a4lq = 1.f;
                if (lq & 1) a4lq *= a4;
                if (lq & 2) a4lq *= a8;
                Wb[nt][1] = E + a4lq * B0;
                if (lq == 3) swv[w][nt * 16 + l15] = Pv + a16 * B0;
            }
        }
    }
    __syncthreads();                       // barrier 1

    // ---- inc + h_prev writes (fp32, own rows) ----
    #pragma unroll
    for (int nt = 0; nt < 4; ++nt) {
        int n = nt * 16 + l15;
        float a = av4[nt], a2 = a * a, a4 = a2 * a2, a8 = a4 * a4, a16 = a8 * a8, a32 = a16 * a16;
        float inc = carry[((size_t)b * NCH + c) * 64 + n];
        for (int ww = 0; ww < w; ++ww) inc = inc * a32 + swv[ww][n];
        float a4lq = 1.f;
        if (lq & 1) a4lq *= a4;
        if (lq & 2) a4lq *= a8;
        #pragma unroll
        for (int tt = 0; tt < 2; ++tt) {
            float Z = Wb[nt][tt] + a4lq * (tt ? a16 : 1.f) * inc;
            float s = Z;
            #pragma unroll
            for (int r = 0; r < 4; ++r) {
                int t = 32 * w + 16 * tt + 4 * lq + r;
                hpk[SWZ(t, n)] = s;           // h_{t-1}
                s = a * s + acc[nt][tt][r];
            }
        }
    }
    // no barrier: all subsequent hpk traffic is own-wave rows

    // ---- P3: y = C.h_prev + Dv*u, tanh -> th (fp32, overwrite h) ----
    #pragma unroll
    for (int tt = 0; tt < 2; ++tt) {
        int tb = 2 * w + tt, trow = tb * 16 + l15, sw = (trow & 7) << 2;
        const float* hw = hpk + trow * 64;
        f16x8 ah[2], al[2];
        #pragma unroll
        for (int kk = 0; kk < 2; ++kk) {
            int kb = kk * 32 + lq * 8;
            float4 v0 = *(const float4*)(hw + (kb ^ sw));
            float4 v1 = *(const float4*)(hw + ((kb + 4) ^ sw));
            float vv[8] = {v0.x, v0.y, v0.z, v0.w, v1.x, v1.y, v1.z, v1.w};
            #pragma unroll
            for (int i = 0; i < 8; ++i) {
                f16 h = (f16)vv[i];
                ah[kk][i] = h;
                al[kk][i] = (f16)(vv[i] - (float)h);
            }
        }
        #pragma unroll
        for (int nt = 0; nt < 4; ++nt) {
            int n = nt * 16 + l15;
            f16x8 ch0 = ldfrag(P.CmH + n * 64 + lq * 8);
            f16x8 ch1 = ldfrag(P.CmH + n * 64 + 32 + lq * 8);
            f16x8 cl0 = ldfrag(P.CmL + n * 64 + lq * 8);
            f16x8 cl1 = ldfrag(P.CmL + n * 64 + 32 + lq * 8);
            f32x4 a4v = {0.f, 0.f, 0.f, 0.f};
            a4v = MFMA(ah[0], ch0, a4v);
            a4v = MFMA(al[0], ch0, a4v);
            a4v = MFMA(ah[0], cl0, a4v);
            a4v = MFMA(ah[1], ch1, a4v);
            a4v = MFMA(al[1], ch1, a4v);
            a4v = MFMA(ah[1], cl1, a4v);
            if (!IN_X) {
                float dv = P.dvv[n];
                f16 dh = (f16)dv, dl = (f16)(dv - (float)dh);
                f16x8 dfh, dfl;
                #pragma unroll
                for (int i2 = 0; i2 < 8; ++i2) { dfh[i2] = (f16)0.f; dfl[i2] = (f16)0.f; }
                int e = ((nt & 1) * 16 + l15) - lq * 8;
                if (e >= 0 && e < 8) { dfh[e] = dh; dfl[e] = dl; }
                a4v = MFMA(ahu[tt][nt >> 1], dfh, a4v);
                a4v = MFMA(ahu[tt][nt >> 1], dfl, a4v);
            }
            float dwin = IN_X ? P.dwin[n] : 0.f;
            #pragma unroll
            for (int r = 0; r < 4; ++r) {
                int t = tb * 16 + lq * 4 + r;
                float y = a4v[r];
                if (IN_X) y += xv[tt][r] * dwin;
                hpk[SWZ(t, n)] = y * rsqrtf(1.f + y * y);
            }
        }
    }

    // ---- P4: o = Wlin.th + blin + u; stage as f16 (low 32 words) or final reduce ----
    f16* stg = (f16*)hpk;
    #pragma unroll
    for (int tt = 0; tt < 2; ++tt) {
        int tb = 2 * w + tt, trow = tb * 16 + l15, sw = (trow & 7) << 2;
        const float* hw = hpk + trow * 64;
        f16x8 t0f, t1f;
        #pragma unroll
        for (int kk = 0; kk < 2; ++kk) {
            int kb = kk * 32 + lq * 8;
            float4 v0 = *(const float4*)(hw + (kb ^ sw));
            float4 v1 = *(const float4*)(hw + ((kb + 4) ^ sw));
            float vv[8] = {v0.x, v0.y, v0.z, v0.w, v1.x, v1.y, v1.z, v1.w};
            #pragma unroll
            for (int i = 0; i < 8; ++i) {
                if (kk == 0) t0f[i] = (f16)vv[i]; else t1f[i] = (f16)vv[i];
            }
        }
        float val[4] = {0.f, 0.f, 0.f, 0.f};
        #pragma unroll
        for (int nt = 0; nt < 4; ++nt) {
            int n = nt * 16 + l15;
            f16x8 w0f = ldfrag(P.WlH + n * 64 + lq * 8);
            f16x8 w1f = ldfrag(P.WlH + n * 64 + 32 + lq * 8);
            f32x4 a4v = {0.f, 0.f, 0.f, 0.f};
            a4v = MFMA(t0f, w0f, a4v);
            a4v = MFMA(t1f, w1f, a4v);
            if (!IN_X) {
                f16x8 ifr;
                #pragma unroll
                for (int i2 = 0; i2 < 8; ++i2) ifr[i2] = (f16)0.f;
                int e = ((nt & 1) * 16 + l15) - lq * 8;
                if (e >= 0 && e < 8) ifr[e] = (f16)1.f;
                a4v = MFMA(ahu[tt][nt >> 1], ifr, a4v);
            }
            float blj = P.blin[n];
            float wij = IN_X ? P.win[n] : 0.f;
            float woj = OUT_FINAL ? P.Wout[n] : 0.f;
            #pragma unroll
            for (int r = 0; r < 4; ++r) {
                int t = tb * 16 + lq * 4 + r;
                float o = a4v[r] + blj;
                if (IN_X) o += xv[tt][r] * wij;
                if (OUT_FINAL) {
                    val[r] += o * woj;
                } else {
                    int g = n >> 1;
                    int word = t * 64 + (((g & ~3) ^ ((t & 7) << 2)) | (g & 3));
                    stg[word * 2 + (n & 1)] = (f16)o;
                }
            }
        }
        if (OUT_FINAL) {
            #pragma unroll
            for (int r = 0; r < 4; ++r) {
                float p = val[r];
                p += __shfl_xor(p, 1);
                p += __shfl_xor(p, 2);
                p += __shfl_xor(p, 4);
                p += __shfl_xor(p, 8);
                if (l15 == 0) out[(size_t)b * T_ + t0 + tb * 16 + lq * 4 + r] = p;
            }
        }
    }

    if (!OUT_FINAL) {
        // ---- coalesced nontemporal store of own 32 rows ----
        #pragma unroll
        for (int i = 0; i < 4; ++i) {
            int row = 32 * w + i * 8 + (lane >> 3);
            int gg = 4 * (lane & 7);
            int word = row * 64 + (gg ^ ((row & 7) << 2));
            u32x4 cv = *(const u32x4*)(hpk + word);
            __builtin_nontemporal_store(cv, (u32x4*)(ug + (size_t)row * 64 + 8 * (lane & 7)));
        }

        // ---- next-layer raw-carry GEMM from staged tile ----
        float partial[4] = {0.f, 0.f, 0.f, 0.f};
        #pragma unroll
        for (int tt = 0; tt < 2; ++tt) {
            int tb = 2 * w + tt, arow = tb * 16 + l15, msk = (arow & 7) << 2;
            U4F8 av0, av1;
            av0.u = *(const u32x4*)(hpk + arow * 64 + ((4 * lq) ^ msk));
            av1.u = *(const u32x4*)(hpk + arow * 64 + ((16 + 4 * lq) ^ msk));
            #pragma unroll
            for (int nt = 0; nt < 4; ++nt) {
                int n = nt * 16 + l15;
                f16x8 bh0 = ldfrag(P.BmHn + n * 64 + lq * 8);
                f16x8 bh1 = ldfrag(P.BmHn + n * 64 + 32 + lq * 8);
                f16x8 bl0 = ldfrag(P.BmLn + n * 64 + lq * 8);
                f16x8 bl1 = ldfrag(P.BmLn + n * 64 + 32 + lq * 8);
                f32x4 a4v = {0.f, 0.f, 0.f, 0.f};
                a4v = MFMA(av0.h, bh0, a4v);
                a4v = MFMA(av0.h, bl0, a4v);
                a4v = MFMA(av1.h, bh1, a4v);
                a4v = MFMA(av1.h, bl1, a4v);
                float4 dp = *(const float4*)(P.atabn + n * 128 + 124 - tb * 16 - lq * 4);
                partial[nt] += a4v[0] * dp.w + a4v[1] * dp.z + a4v[2] * dp.y + a4v[3] * dp.x;
            }
        }
        #pragma unroll
        for (int nt = 0; nt < 4; ++nt) {
            float v = partial[nt];
            v += __shfl_xor(v, 16);
            v += __shfl_xor(v, 32);
            if (lq == 0) red[w][nt * 16 + l15] = v;
        }
        __syncthreads();                   // barrier 2
        if (w == 0)
            carry[((size_t)b * NCH + c) * 64 + lane] =
                red[0][lane] + red[1][lane] + red[2][lane] + red[3][lane];
    }
}

// ---------- host ----------
extern "C" void kernel_launch(void* const* d_in, const int* in_sizes, int n_in,
                              void* d_out, int out_size, void* d_ws, size_t ws_size,
                              hipStream_t stream)
{
    const float* x   = (const float*)d_in[0];
    const float* Win = (const float*)d_in[1];
    const float* nu  = (const float*)d_in[2];
    const float* ga  = (const float*)d_in[3];
    const float* Bm  = (const float*)d_in[4];
    const float* Cm  = (const float*)d_in[5];
    const float* Dv  = (const float*)d_in[6];
    const float* Wl  = (const float*)d_in[7];
    const float* bl  = (const float*)d_in[8];
    const float* Wo  = (const float*)d_in[9];
    float* out = (float*)d_out;

    char* p = (char*)d_ws;
    f16* ubuf = (f16*)p;            p += (size_t)B_ * T_ * 64 * sizeof(f16);
    float* carry = (float*)p;       p += (size_t)B_ * NCH * 64 * sizeof(float);
    f16* wBmH = (f16*)p;            p += 4 * 4096 * sizeof(f16);
    f16* wBmL = (f16*)p;            p += 4 * 4096 * sizeof(f16);
    f16* wCmH = (f16*)p;            p += 4 * 4096 * sizeof(f16);
    f16* wCmL = (f16*)p;            p += 4 * 4096 * sizeof(f16);
    f16* wWlH = (f16*)p;            p += 4 * 4096 * sizeof(f16);
    float* atab = (float*)p;        p += 4 * 8192 * sizeof(float);
    float* sc = (float*)p;          p += 4 * 320 * sizeof(float);

    dim3 grid(B_ * NCH), blk256(256), blk64(64), gscan(B_);

    prep<<<1, 256, 0, stream>>>(Win, nu, ga, Bm, Cm, Dv, Wl,
                                wBmH, wBmL, wCmH, wCmL, wWlH, atab, sc);
    carry_x<<<grid, blk64, 0, stream>>>(x, sc, carry);

    for (int l = 0; l < DEPTH_; ++l) {
        int ln = (l + 1 < DEPTH_) ? l + 1 : l;
        scan_carry<<<gscan, blk256, 0, stream>>>(nu + l * 64, carry);
        LPrep Pr;
        Pr.BmH = wBmH + l * 4096;  Pr.BmL = wBmL + l * 4096;
        Pr.CmH = wCmH + l * 4096;  Pr.CmL = wCmL + l * 4096;
        Pr.WlH = wWlH + l * 4096;
        Pr.av = sc + l * 320;       Pr.dvv = sc + l * 320 + 64;
        Pr.bw = sc + l * 320 + 128; Pr.dwin = sc + l * 320 + 192;
        Pr.win = sc + l * 320 + 256;
        Pr.BmHn = wBmH + ln * 4096; Pr.BmLn = wBmL + ln * 4096;
        Pr.atabn = atab + ln * 8192;
        Pr.blin = bl + l * 64; Pr.Wout = Wo;
        if (l == 0)
            lru_fused<1, 0><<<grid, blk256, 0, stream>>>(x, ubuf, Pr, carry, out);
        else if (l == DEPTH_ - 1)
            lru_fused<0, 1><<<grid, blk256, 0, stream>>>(x, ubuf, Pr, carry, out);
        else
            lru_fused<0, 0><<<grid, blk256, 0, stream>>>(x, ubuf, Pr, carry, out);
    }
}